// Round 6
// baseline (190.043 us; speedup 1.0000x reference)
//
#include <hip/hip_runtime.h>

// RecurrentCrossLinearAttention: N=16, S=4096, H=16, D=64, M=64, fp32.
// Round 6: make the software pipeline REAL.
//  r5 failure mode (VGPR=88 proves it): compiler sank prefetch loads to
//  their uses -> depth-0 pipeline -> ~2400 stall cyc/chunk (K vmcnt + V
//  vmcnt + LDS turnaround). Fixes:
//   (a) stage-AHEAD double-buffered K in LDS (write chunk c+1 before
//       computing chunk c): LDS turnaround off the critical path
//   (b) ping-pong V register buffers, static parity via c+=2 pair loop
//       (2-row chunks so total ~126 VGPR fits the (512,2) 128 cap)
//   (c) sched_barrier(0) after each refill cluster: forbid sinking the
//       prefetch loads downward (the r5 collapse)
// Shell proven r3/r5: 512 thr, launch_bounds(512,2), grid 256 = 1 block/CU.

#define S_LEN  4096
#define NHEAD  16
#define DDIM   64
#define MDIM   64
#define NWAVE  8
#define RPW    (S_LEN / NWAVE)    // 512 rows per wave
#define NCH    (RPW / 2)          // 256 two-row chunks

#define OUT_SOFF  (16 * 16 * 64)
#define OUT_ZOFF  (OUT_SOFF + 16 * 16 * 64 * 64)

__device__ __forceinline__ float elup1(float x) {
    // elu(x) + 1 = x+1 (x>0) else exp(x)
    return x > 0.0f ? x + 1.0f : __expf(x);
}

// stage chunk: elu+mask K, accumulate z, write per-wave LDS slot sp
#define STAGE(sp, KC, MC) do {                                              \
    float2 kt_;                                                             \
    kt_.x = elup1(KC.x) * (MC);  kt_.y = elup1(KC.y) * (MC);                \
    zst.x += kt_.x;  zst.y += kt_.y;                                        \
    *(float2*)&Kd[sp][wave][srow][scol] = kt_;                              \
} while (0)

// compute one 2-row chunk from LDS slot P and V register buffer VC
#define COMPUTE(P, VC) do {                                                 \
    _Pragma("unroll")                                                       \
    for (int r_ = 0; r_ < 2; ++r_) {                                        \
        const float4 kk0 = *(const float4*)&Kd[P][wave][r_][d0];            \
        const float4 kk1 = *(const float4*)&Kd[P][wave][r_][d0 + 4];        \
        const float4 va_ = VC[2 * r_], vb_ = VC[2 * r_ + 1];                \
        const float kvv[8] = {kk0.x, kk0.y, kk0.z, kk0.w,                   \
                              kk1.x, kk1.y, kk1.z, kk1.w};                  \
        const float vmv[8] = {va_.x, va_.y, va_.z, va_.w,                   \
                              vb_.x, vb_.y, vb_.z, vb_.w};                  \
        _Pragma("unroll")                                                   \
        for (int mi = 0; mi < 8; ++mi)                                      \
            _Pragma("unroll")                                               \
            for (int di = 0; di < 8; ++di)                                  \
                acc[mi][di] = fmaf(vmv[mi], kvv[di], acc[mi][di]);          \
    }                                                                       \
} while (0)

#define VLOAD(VC) do {                                                      \
    VC[0] = *(const float4*)vpA;  VC[1] = *(const float4*)(vpA + 4);        \
    VC[2] = *(const float4*)vpB;  VC[3] = *(const float4*)(vpB + 4);        \
    vpA += STEP2;  vpB += STEP2;                                            \
} while (0)

#define KLOAD(KC, MC) do {                                                  \
    KC = *(const float2*)kp;  MC = *mp;  kp += STEP2;  mp += 2;             \
} while (0)

__global__ __launch_bounds__(512, 2)
void rcla_fused(const float* __restrict__ query,
                const float* __restrict__ keys,
                const float* __restrict__ values,
                const float* __restrict__ kmask,
                float* __restrict__ out)
{
    __shared__ float Kd[2][NWAVE][2][DDIM];    // 8 KB double-buffered K
    __shared__ float buf2[2][MDIM * DDIM];     // 32 KB merge buffers
    __shared__ float zb2[2][DDIM];
    __shared__ float qb[DDIM];

    const int t    = threadIdx.x;
    const int wave = t >> 6;
    const int lane = t & 63;
    const int pair = blockIdx.x;               // n*16 + h
    const int nIdx = pair >> 4;
    const int hIdx = pair & 15;

    const int srow = lane >> 5;                // 0..1 staging row in chunk
    const int scol = (lane & 31) * 2;          // 2 K cols per lane
    const int m0   = (lane >> 3) * 8;          // acc tile rows (V side)
    const int d0   = (lane & 7) * 8;           // acc tile cols (K side)

    const size_t rowStride = (size_t)NHEAD * DDIM;   // 1024 floats
    const int    sBase = wave * RPW;
    const size_t STEP2 = 2 * rowStride;

    const float* kp  = keys + ((size_t)nIdx * S_LEN + sBase + srow) * rowStride
                     + (size_t)hIdx * DDIM + scol;
    const float* mp  = kmask + (size_t)nIdx * S_LEN + sBase + srow;
    const float* vpA = values + ((size_t)nIdx * S_LEN + sBase) * rowStride
                     + (size_t)hIdx * DDIM + m0;
    const float* vpB = vpA + rowStride;

    float acc[8][8];
#pragma unroll
    for (int i = 0; i < 8; ++i)
#pragma unroll
        for (int j = 0; j < 8; ++j) acc[i][j] = 0.0f;
    float2 zst = make_float2(0.0f, 0.0f);

    float2 KC0, KC1;  float MC0, MC1;
    float4 VC0[4], VC1[4];

    // ---- prologue: chunks 0,1 in flight; stage 0; refill K buffer to c2 ----
    KLOAD(KC0, MC0);               // chunk 0
    VLOAD(VC0);
    KLOAD(KC1, MC1);               // chunk 1
    VLOAD(VC1);
    STAGE(0, KC0, MC0);            // slot0 <- chunk 0
    KLOAD(KC0, MC0);               // chunk 2 (3-deep K pipeline)

    // ---- main loop: pairs of chunks, static buffer parity ----
    for (int c = 0; c < NCH; c += 2) {
        STAGE(1, KC1, MC1);                        // stage chunk c+1
        if (c + 3 < NCH) KLOAD(KC1, MC1);          // K chunk c+3 in flight
        COMPUTE(0, VC0);                           // chunk c
        if (c + 2 < NCH) VLOAD(VC0);               // V chunk c+2 in flight
        __builtin_amdgcn_sched_barrier(0);         // don't sink loads below

        if (c + 2 < NCH) {
            STAGE(0, KC0, MC0);                    // stage chunk c+2
            if (c + 4 < NCH) KLOAD(KC0, MC0);      // K chunk c+4 in flight
        }
        COMPUTE(1, VC1);                           // chunk c+1
        if (c + 3 < NCH) VLOAD(VC1);               // V chunk c+3 in flight
        __builtin_amdgcn_sched_barrier(0);
    }

    // ---- z: combine the two srow groups (lanes ^32) ----
    zst.x += __shfl_xor(zst.x, 32, 64);
    zst.y += __shfl_xor(zst.y, 32, 64);

    __syncthreads();                               // all waves done streaming
    if (t < DDIM) qb[t] = elup1(query[(size_t)pair * DDIM + t]);

    // ---- merge 8 wave-partials -> 2 buffers, 4 barriered rounds ----
    const int g = wave >> 2;
    float* mb = &buf2[g][0];
    for (int rr = 0; rr < 4; ++rr) {
        if ((wave & 3) == rr) {
#pragma unroll
            for (int mi = 0; mi < 8; ++mi) {
                float4* row = (float4*)&mb[(m0 + mi) * DDIM + d0];
                if (rr == 0) {
                    row[0] = make_float4(acc[mi][0], acc[mi][1], acc[mi][2], acc[mi][3]);
                    row[1] = make_float4(acc[mi][4], acc[mi][5], acc[mi][6], acc[mi][7]);
                } else {
                    float4 a = row[0], b = row[1];
                    a.x += acc[mi][0]; a.y += acc[mi][1]; a.z += acc[mi][2]; a.w += acc[mi][3];
                    b.x += acc[mi][4]; b.y += acc[mi][5]; b.z += acc[mi][6]; b.w += acc[mi][7];
                    row[0] = a; row[1] = b;
                }
            }
            if (lane < 32) {
                if (rr == 0) { zb2[g][scol] = zst.x;  zb2[g][scol + 1] = zst.y; }
                else         { zb2[g][scol] += zst.x; zb2[g][scol + 1] += zst.y; }
            }
        }
        __syncthreads();
    }

    // ---- final 2-way sum; write S_state; keep copy for epilogue ----
    {
        const int e = t * 8;                       // 512 threads x 8 = 4096
        float4 a0 = *(const float4*)&buf2[0][e];
        float4 a1 = *(const float4*)&buf2[0][e + 4];
        const float4 b0 = *(const float4*)&buf2[1][e];
        const float4 b1 = *(const float4*)&buf2[1][e + 4];
        a0.x += b0.x; a0.y += b0.y; a0.z += b0.z; a0.w += b0.w;
        a1.x += b1.x; a1.y += b1.y; a1.z += b1.z; a1.w += b1.w;
        float* dst = out + OUT_SOFF + (size_t)pair * (MDIM * DDIM) + e;
        *(float4*)dst       = a0;
        *(float4*)(dst + 4) = a1;
        *(float4*)&buf2[0][e]     = a0;
        *(float4*)&buf2[0][e + 4] = a1;
    }
    if (t < DDIM) {
        const float zv = zb2[0][t] + zb2[1][t];
        out[OUT_ZOFF + (size_t)pair * DDIM + t] = zv;
        zb2[0][t] = zv;
    }
    __syncthreads();

    // ---- epilogue: wave 0, lane = m ----
    if (wave == 0) {
        float zp = qb[lane] * zb2[0][lane];
#pragma unroll
        for (int off = 32; off >= 1; off >>= 1) zp += __shfl_xor(zp, off, 64);
        const float qz = 1.0f / (zp + 1e-6f);
        float vs = 0.0f;
#pragma unroll
        for (int d = 0; d < DDIM; d += 4) {
            const float4 sv = *(const float4*)&buf2[0][lane * DDIM + d];
            vs = fmaf(qb[d],     sv.x, vs);
            vs = fmaf(qb[d + 1], sv.y, vs);
            vs = fmaf(qb[d + 2], sv.z, vs);
            vs = fmaf(qb[d + 3], sv.w, vs);
        }
        out[(size_t)pair * MDIM + lane] = qz * vs;
    }
}

extern "C" void kernel_launch(void* const* d_in, const int* in_sizes, int n_in,
                              void* d_out, int out_size, void* d_ws, size_t ws_size,
                              hipStream_t stream) {
    const float* q  = (const float*)d_in[0];
    const float* k  = (const float*)d_in[1];
    const float* v  = (const float*)d_in[2];
    const float* km = (const float*)d_in[3];
    float* out = (float*)d_out;
    rcla_fused<<<dim3(256), dim3(512), 0, stream>>>(q, k, v, km, out);
}

// Round 8
// 103.468 us; speedup vs baseline: 1.8367x; 1.8367x over previous
//
#include <hip/hip_runtime.h>

// RecurrentCrossLinearAttention: N=16, S=4096, H=16, D=64, M=64, fp32.
// Round 8: r7 MFMA structure + aliasing fix.
//  r7 failure mode: barrier-free hot loop + TYPE-PUNNED LDS access
//  (unsigned stores vs short8 loads) let strict-aliasing reorder the
//  fragment ds_reads above the staging ds_writes -> stale data -> scramble
//  (absmax 317 ~ scramble magnitude; V_out passed only because its values
//  are ~1e-3). Fix: single access type (unsigned stores, uint4 vector
//  loads union-cast to short8) + zero-cost asm memory fences around the
//  stage->read boundary. HW side is safe (per-wave in-order DS pipe,
//  r5-validated); only compiler ordering needed fixing.
// Shell: grid 256 (1 block/CU), 512 thr, launch_bounds(512,1) (VGPR cap
// 256 -- kills the r2/r4 spill mode; LDS 117 KB forces 1 block/CU anyway).

#define S_LEN  4096
#define NHEAD  16
#define DDIM   64
#define MDIM   64
#define NWAVE  8
#define RPW    (S_LEN / NWAVE)    // 512 rows per wave
#define CH_S   32                 // s-rows per chunk
#define NCHK   (RPW / CH_S)       // 16 chunks per wave
#define KP32   20                 // u32 per LDS row: 16 data + 4 pad (80 B)

#define OUT_SOFF  (16 * 16 * 64)
#define OUT_ZOFF  (OUT_SOFF + 16 * 16 * 64 * 64)

using short8 = __attribute__((ext_vector_type(8))) short;
using f32x4  = __attribute__((ext_vector_type(4))) float;
using uint4v = __attribute__((ext_vector_type(4))) unsigned int;

union FragCast { uint4v u; short8 s; };

__device__ __forceinline__ float elup1(float x) {
    // elu(x) + 1 = x+1 (x>0) else exp(x)
    return x > 0.0f ? x + 1.0f : __expf(x);
}

// pack two fp32 -> {lo=bf16(a), hi=bf16(b)} with round-to-nearest-even
__device__ __forceinline__ unsigned bfpack(float a, float b) {
    union { float f; unsigned u; } ca, cb;
    ca.f = a; cb.f = b;
    const unsigned ra = ca.u + 0x7FFFu + ((ca.u >> 16) & 1u);
    const unsigned rb = cb.u + 0x7FFFu + ((cb.u >> 16) & 1u);
    return (ra >> 16) | (rb & 0xFFFF0000u);
}

__global__ __launch_bounds__(512, 1)
void rcla_mfma(const float* __restrict__ query,
               const float* __restrict__ keys,
               const float* __restrict__ values,
               const float* __restrict__ kmask,
               float* __restrict__ out)
{
    // u32-typed transposed tiles: Ktu[d][s-pair], Vtu[m][s-pair], bf16x2/u32
    __shared__ unsigned Ktu[NWAVE][DDIM][KP32];   // 40 KB
    __shared__ unsigned Vtu[NWAVE][MDIM][KP32];   // 40 KB
    __shared__ float buf2[2][64][68];             // 34 KB merge (padded rows)
    __shared__ float zb2[2][DDIM];
    __shared__ float qb[DDIM];

    const int t    = threadIdx.x;
    const int wave = t >> 6;
    const int lane = t & 63;
    const int c16  = lane & 15;                // free index (m for A, d for B)
    const int g    = lane >> 4;                // k-group 0..3
    const int pair = blockIdx.x;               // n*16 + h
    const int nIdx = pair >> 4;
    const int hIdx = pair & 15;

    const int d0s  = c16 * 4;                  // staging: 4 consecutive d (or m)

    const size_t rowStride = (size_t)NHEAD * DDIM;     // 1024 floats
    const size_t base = ((size_t)nIdx * S_LEN + (size_t)wave * RPW) * rowStride
                      + (size_t)hIdx * DDIM;
    const float* kbase = keys   + base;
    const float* vbase = values + base;
    const float* mbase = kmask + (size_t)nIdx * S_LEN + wave * RPW;

    f32x4 acc[4][4];
#pragma unroll
    for (int i = 0; i < 4; ++i)
#pragma unroll
        for (int j = 0; j < 4; ++j) acc[i][j] = f32x4{0.f, 0.f, 0.f, 0.f};
    float4 zacc = make_float4(0.f, 0.f, 0.f, 0.f);

    for (int ch = 0; ch < NCHK; ++ch) {
        const int scg = ch * CH_S + g * 8;     // this lane's first s in chunk

        // ---- K phase: load 8 rows, elu+mask, z, pack bf16, transposed store ----
#pragma unroll
        for (int q = 0; q < 4; ++q) {
            const int sp = g * 4 + q;          // u32 column (s-pair index)
            const int sl = scg + 2 * q;        // wave-local s (even)
            const float* kp = kbase + (size_t)sl * rowStride + d0s;
            const float4 k1 = *(const float4*)kp;
            const float4 k2 = *(const float4*)(kp + rowStride);
            const float2 mm = *(const float2*)(mbase + sl);
            const float a0 = elup1(k1.x) * mm.x, a1 = elup1(k1.y) * mm.x;
            const float a2 = elup1(k1.z) * mm.x, a3 = elup1(k1.w) * mm.x;
            const float b0 = elup1(k2.x) * mm.y, b1 = elup1(k2.y) * mm.y;
            const float b2 = elup1(k2.z) * mm.y, b3 = elup1(k2.w) * mm.y;
            zacc.x += a0 + b0;  zacc.y += a1 + b1;
            zacc.z += a2 + b2;  zacc.w += a3 + b3;
            Ktu[wave][d0s + 0][sp] = bfpack(a0, b0);
            Ktu[wave][d0s + 1][sp] = bfpack(a1, b1);
            Ktu[wave][d0s + 2][sp] = bfpack(a2, b2);
            Ktu[wave][d0s + 3][sp] = bfpack(a3, b3);
        }

        // ---- V phase: load 8 rows, pack bf16, transposed store ----
#pragma unroll
        for (int q = 0; q < 4; ++q) {
            const int sp = g * 4 + q;
            const int sl = scg + 2 * q;
            const float* vp = vbase + (size_t)sl * rowStride + d0s;
            const float4 v1 = *(const float4*)vp;
            const float4 v2 = *(const float4*)(vp + rowStride);
            Vtu[wave][d0s + 0][sp] = bfpack(v1.x, v2.x);
            Vtu[wave][d0s + 1][sp] = bfpack(v1.y, v2.y);
            Vtu[wave][d0s + 2][sp] = bfpack(v1.z, v2.z);
            Vtu[wave][d0s + 3][sp] = bfpack(v1.w, v2.w);
        }

        // compiler fence: staging stores must precede fragment loads
        // (HW: per-wave in-order DS pipe; zero instructions emitted)
        asm volatile("" ::: "memory");

        // ---- fragment loads: 8 consecutive s (= u32 cols g*4..g*4+3) ----
        short8 af[4], bff[4];
#pragma unroll
        for (int ti = 0; ti < 4; ++ti) {
            FragCast fc;
            fc.u = *(const uint4v*)&Vtu[wave][ti * 16 + c16][g * 4];
            af[ti] = fc.s;
        }
#pragma unroll
        for (int tj = 0; tj < 4; ++tj) {
            FragCast fc;
            fc.u = *(const uint4v*)&Ktu[wave][tj * 16 + c16][g * 4];
            bff[tj] = fc.s;
        }

        // compiler fence: fragment loads precede next chunk's stores;
        // next chunk's global loads may still overlap the MFMA cluster
        asm volatile("" ::: "memory");

        // ---- MFMA: 16 tiles of 16x16, A = V^T (free=m), B = K (free=d) ----
#pragma unroll
        for (int ti = 0; ti < 4; ++ti)
#pragma unroll
            for (int tj = 0; tj < 4; ++tj)
                acc[ti][tj] = __builtin_amdgcn_mfma_f32_16x16x32_bf16(
                    af[ti], bff[tj], acc[ti][tj], 0, 0, 0);
    }

    // ---- z: sum over the 4 k-groups (lanes xor 16, 32) ----
    zacc.x += __shfl_xor(zacc.x, 16, 64); zacc.y += __shfl_xor(zacc.y, 16, 64);
    zacc.z += __shfl_xor(zacc.z, 16, 64); zacc.w += __shfl_xor(zacc.w, 16, 64);
    zacc.x += __shfl_xor(zacc.x, 32, 64); zacc.y += __shfl_xor(zacc.y, 32, 64);
    zacc.z += __shfl_xor(zacc.z, 32, 64); zacc.w += __shfl_xor(zacc.w, 32, 64);

    __syncthreads();                           // all waves done streaming
    if (t < DDIM) qb[t] = elup1(query[(size_t)pair * DDIM + t]);

    // ---- merge 8 wave-partials -> 2 buffers, 4 barriered rounds ----
    // D-layout [HW-verified m89]: row m = ti*16 + (lane>>4)*4 + reg,
    //                             col d = tj*16 + (lane&15)
    const int grp = wave >> 2;
    for (int rr = 0; rr < 4; ++rr) {
        if ((wave & 3) == rr) {
#pragma unroll
            for (int ti = 0; ti < 4; ++ti)
#pragma unroll
                for (int tj = 0; tj < 4; ++tj)
#pragma unroll
                    for (int r = 0; r < 4; ++r) {
                        const int m = ti * 16 + g * 4 + r;
                        const int d = tj * 16 + c16;
                        if (rr == 0) buf2[grp][m][d]  = acc[ti][tj][r];
                        else         buf2[grp][m][d] += acc[ti][tj][r];
                    }
            if (lane < 16) {
                if (rr == 0) {
                    zb2[grp][d0s]     = zacc.x;  zb2[grp][d0s + 1] = zacc.y;
                    zb2[grp][d0s + 2] = zacc.z;  zb2[grp][d0s + 3] = zacc.w;
                } else {
                    zb2[grp][d0s]     += zacc.x; zb2[grp][d0s + 1] += zacc.y;
                    zb2[grp][d0s + 2] += zacc.z; zb2[grp][d0s + 3] += zacc.w;
                }
            }
        }
        __syncthreads();
    }

    // ---- final 2-way sum; write S_state; keep copy for epilogue ----
    {
        const int m  = t >> 3;
        const int dc = (t & 7) * 8;
        float4 a0 = *(const float4*)&buf2[0][m][dc];
        float4 a1 = *(const float4*)&buf2[0][m][dc + 4];
        const float4 b0 = *(const float4*)&buf2[1][m][dc];
        const float4 b1 = *(const float4*)&buf2[1][m][dc + 4];
        a0.x += b0.x; a0.y += b0.y; a0.z += b0.z; a0.w += b0.w;
        a1.x += b1.x; a1.y += b1.y; a1.z += b1.z; a1.w += b1.w;
        float* dst = out + OUT_SOFF + ((size_t)pair * MDIM + m) * DDIM + dc;
        *(float4*)dst       = a0;
        *(float4*)(dst + 4) = a1;
        *(float4*)&buf2[0][m][dc]     = a0;
        *(float4*)&buf2[0][m][dc + 4] = a1;
    }
    if (t < DDIM) {
        const float zv = zb2[0][t] + zb2[1][t];
        out[OUT_ZOFF + (size_t)pair * DDIM + t] = zv;
        zb2[0][t] = zv;
    }
    __syncthreads();

    // ---- epilogue: wave 0, lane = m ----
    if (wave == 0) {
        float zp = qb[lane] * zb2[0][lane];
#pragma unroll
        for (int off = 32; off >= 1; off >>= 1) zp += __shfl_xor(zp, off, 64);
        const float qz = 1.0f / (zp + 1e-6f);
        float vs = 0.0f;
#pragma unroll
        for (int d = 0; d < DDIM; d += 4) {
            const float4 sv = *(const float4*)&buf2[0][lane][d];
            vs = fmaf(qb[d],     sv.x, vs);
            vs = fmaf(qb[d + 1], sv.y, vs);
            vs = fmaf(qb[d + 2], sv.z, vs);
            vs = fmaf(qb[d + 3], sv.w, vs);
        }
        out[(size_t)pair * MDIM + lane] = qz * vs;
    }
}

extern "C" void kernel_launch(void* const* d_in, const int* in_sizes, int n_in,
                              void* d_out, int out_size, void* d_ws, size_t ws_size,
                              hipStream_t stream) {
    const float* q  = (const float*)d_in[0];
    const float* k  = (const float*)d_in[1];
    const float* v  = (const float*)d_in[2];
    const float* km = (const float*)d_in[3];
    float* out = (float*)d_out;
    rcla_mfma<<<dim3(256), dim3(512), 0, stream>>>(q, k, v, km, out);
}